// Round 9
// baseline (79.147 us; speedup 1.0000x reference)
//
#include <hip/hip_runtime.h>
#include <math.h>

// Problem constants: z [4,32,32,32] f32, embedding [32768,32] f32.
constexpr int Bc   = 4;
constexpr int Dc   = 32;
constexpr int HWc  = 1024;
constexpr int NE   = 32768;
constexpr int POS  = Bc * HWc;        // 4096 positions

typedef _Float16 f16x8 __attribute__((ext_vector_type(8)));
typedef float    f32x4 __attribute__((ext_vector_type(4)));

// Monotonic float->uint encoding; pack with ~idx so that among equal values
// the SMALLER index wins under max (== jnp.argmax first-index rule).
__device__ inline unsigned long long packVI(float v, int idx) {
    unsigned u = __float_as_uint(v);
    u = (u & 0x80000000u) ? ~u : (u | 0x80000000u);
    return ((unsigned long long)u << 32) | (unsigned)(~idx);
}

// Prep: embedding fp32 [32768][32] -> Es fp16 [32768][64]: cols 0..31 = hi
// (RNE fp16 of x), cols 32..63 = lo (fp16 of x - hi). hi+lo = x to ~2^-22.
// Also zeroes best[] (first 4096 threads) so no separate memset dispatch.
__global__ __launch_bounds__(256) void vq_eprep(
    const float* __restrict__ emb, _Float16* __restrict__ Es,
    unsigned long long* __restrict__ best)
{
    const int c = blockIdx.x * 256 + threadIdx.x;       // 0..32767
    if (c < POS) best[c] = 0ULL;   // encoded minimum: any real value wins

    const float4* src = reinterpret_cast<const float4*>(emb + (size_t)c * Dc);
    float x[Dc];
#pragma unroll
    for (int q = 0; q < 8; ++q) {
        const float4 v = src[q];
        x[4*q+0] = v.x; x[4*q+1] = v.y; x[4*q+2] = v.z; x[4*q+3] = v.w;
    }
    f16x8* dst = reinterpret_cast<f16x8*>(Es + (size_t)c * 64);
#pragma unroll
    for (int q = 0; q < 4; ++q) {
        f16x8 h, l;
#pragma unroll
        for (int r = 0; r < 8; ++r) {
            const float xv = x[8*q+r];
            const _Float16 hv = (_Float16)xv;
            h[r] = hv;
            l[r] = (_Float16)(xv - (float)hv);
        }
        dst[q]     = h;   // hi block
        dst[4 + q] = l;   // lo block
    }
}

// Main: logits via MFMA f32_16x16x32_f16, split-fp16 exact (hi*hi + hi*lo +
// lo*hi; dropped lo*lo ~2e-6). Round-9 schedule: 2 pos-tiles/wave (32
// positions) -> ~70 live VGPRs -> 6 waves/SIMD (round 8: 4 tiles, 176 VGPR,
// 3 waves/SIMD, 60% stall). B tile register-double-buffered: prefetch ct+1
// while computing ct. Block's 4 waves share one XCD-pinned 512-code chunk.
// Layout contract (HW-verified m89/m91, validated exact in round 8):
// A row / B col / D col = lane&15; D row-within-tile = 4*(lane>>4)+reg.
// k-slot (g=lane>>4, q) filled identically for A and B so the true k-mapping
// bijection cancels.
__global__ __launch_bounds__(256, 6) void vq_mfma(
    const float* __restrict__ z, const _Float16* __restrict__ Es,
    unsigned long long* __restrict__ best)
{
    const int lin  = blockIdx.x;          // 0..2047
    const int xcd  = lin & 7;             // dispatch round-robins XCDs
    const int j    = lin >> 3;            // 0..255
    const int chunk = xcd * 8 + (j & 7);  // 64 chunks x 512 codes, 8 per XCD
    const int pblk  = j >> 3;             // 32 pos-blocks of 128
    const int wave  = threadIdx.x >> 6;
    const int lane  = threadIdx.x & 63;
    const int m = lane & 15, g = lane >> 4;

    const int posBase = pblk * 128 + wave * 32;

    // ---- A fragments: 2 pos-tiles x (hi,lo), dimension d=8g+q at slot q ----
    f16x8 Ahi[2], Alo[2];
#pragma unroll
    for (int t = 0; t < 2; ++t) {
        const int pos = posBase + t * 16 + m;
        const int b = pos >> 10, hw = pos & (HWc - 1);
        const float* zp = z + (size_t)b * Dc * HWc + hw;
#pragma unroll
        for (int q = 0; q < 8; ++q) {
            const float xv = zp[(size_t)(8 * g + q) * HWc];
            const _Float16 hv = (_Float16)xv;
            Ahi[t][q] = hv;
            Alo[t][q] = (_Float16)(xv - (float)hv);
        }
    }
#pragma unroll
    for (int t = 0; t < 2; ++t) asm volatile("" : "+v"(Ahi[t]), "+v"(Alo[t]));

    float bval[8];
    int   bidx[8];
#pragma unroll
    for (int i = 0; i < 8; ++i) { bval[i] = -INFINITY; bidx[i] = 0; }

    const int cbase = chunk * 512;
    const _Float16* ep = Es + (size_t)(cbase + m) * 64 + 8 * g;

    // prologue: load tile 0's B fragments
    f16x8 Bh = *reinterpret_cast<const f16x8*>(ep);
    f16x8 Bl = *reinterpret_cast<const f16x8*>(ep + 32);
    int idxv = cbase + m;

#pragma unroll 2
    for (int ct = 0; ct < 32; ++ct) {             // 32 code-tiles of 16
        // prefetch next tile (wrap-reload current on last iter: in-L1, cheap)
        const _Float16* epn = ep + (ct < 31 ? 16 * 64 : 0);
        const f16x8 Bh_n = *reinterpret_cast<const f16x8*>(epn);
        const f16x8 Bl_n = *reinterpret_cast<const f16x8*>(epn + 32);
        ep = epn;

#pragma unroll
        for (int t = 0; t < 2; ++t) {
            f32x4 acc = {0.f, 0.f, 0.f, 0.f};
            acc = __builtin_amdgcn_mfma_f32_16x16x32_f16(Ahi[t], Bh, acc, 0, 0, 0);
            acc = __builtin_amdgcn_mfma_f32_16x16x32_f16(Ahi[t], Bl, acc, 0, 0, 0);
            acc = __builtin_amdgcn_mfma_f32_16x16x32_f16(Alo[t], Bh, acc, 0, 0, 0);
#pragma unroll
            for (int r = 0; r < 4; ++r) {
                if (acc[r] > bval[t*4+r]) { bval[t*4+r] = acc[r]; bidx[t*4+r] = idxv; }
            }
        }
        idxv += 16;
        Bh = Bh_n; Bl = Bl_n;
    }

    // ---- pack (val,~idx), reduce across the 16 cols of each lane group ----
    unsigned long long pk[8];
#pragma unroll
    for (int i = 0; i < 8; ++i) pk[i] = packVI(bval[i], bidx[i]);
#pragma unroll
    for (int s = 1; s < 16; s <<= 1) {
#pragma unroll
        for (int i = 0; i < 8; ++i) {
            const unsigned long long o = __shfl_xor(pk[i], s, 64);
            if (o > pk[i]) pk[i] = o;
        }
    }
    // lane g*16+m, m<8 commits pair (t=m>>2, r=m&3): row = base+t*16+4g+r.
    unsigned long long mine = pk[0];
#pragma unroll
    for (int i = 1; i < 8; ++i) if (m == i) mine = pk[i];   // static-index select
    if (m < 8) {
        const int row = posBase + (m >> 2) * 16 + 4 * g + (m & 3);
        atomicMax(best + row, mine);
    }
}

// Fallback (ws too small for Es): round-7 scalar VALU scan, all 256 segments.
__global__ __launch_bounds__(256, 4) void vq_scalar(
    const float* __restrict__ z, const float* __restrict__ emb,
    unsigned long long* __restrict__ best)
{
    const int lin = blockIdx.x;           // 0..2047
    const int xcd = lin & 7, j = lin >> 3;
    const int seg    = xcd * 32 + (j & 31);   // 256 segments of 128 codes
    const int posgrp = j >> 5;                // 0..7

    const int t  = posgrp * 256 + threadIdx.x;
    const int p0 = t, p1 = t + POS / 2;
    const int b0 = p0 >> 10, hw0 = p0 & (HWc - 1);
    const int b1 = p1 >> 10, hw1 = p1 & (HWc - 1);
    const float* zp0 = z + (size_t)b0 * Dc * HWc + hw0;
    const float* zp1 = z + (size_t)b1 * Dc * HWc + hw1;

    float za[Dc], zb[Dc];
#pragma unroll
    for (int d = 0; d < Dc; ++d) {
        za[d] = zp0[(size_t)d * HWc];
        zb[d] = zp1[(size_t)d * HWc];
    }
#pragma unroll
    for (int d = 0; d < Dc; ++d) asm volatile("" : "+v"(za[d]), "+v"(zb[d]));

    const int c0 = seg * 128;
    const float4* e4 = reinterpret_cast<const float4*>(emb + (size_t)c0 * Dc);
    float v0 = -INFINITY, v1 = -INFINITY;
    int   i0 = c0, i1 = c0;
#pragma unroll 1
    for (int cc = 0; cc < 128; ++cc, e4 += 8) {
        float a0 = 0.f, a1 = 0.f;
#pragma unroll
        for (int q = 0; q < 8; ++q) {
            const float4 e = e4[q];
            a0 = fmaf(za[4*q+0], e.x, a0); a1 = fmaf(zb[4*q+0], e.x, a1);
            a0 = fmaf(za[4*q+1], e.y, a0); a1 = fmaf(zb[4*q+1], e.y, a1);
            a0 = fmaf(za[4*q+2], e.z, a0); a1 = fmaf(zb[4*q+2], e.z, a1);
            a0 = fmaf(za[4*q+3], e.w, a0); a1 = fmaf(zb[4*q+3], e.w, a1);
        }
        const int c = c0 + cc;
        if (a0 > v0) { v0 = a0; i0 = c; }
        if (a1 > v1) { v1 = a1; i1 = c; }
    }
    atomicMax(best + p0, packVI(v0, i0));
    atomicMax(best + p1, packVI(v1, i1));
}

// Finish: decode winner, gather embedding row (float4, exact fp32 values),
// write z_q [b,d,h,w] coalesced, index as float (<=32767 exact in fp32).
__global__ __launch_bounds__(256) void vq_finish_kernel(
    const unsigned long long* __restrict__ best, const float* __restrict__ emb,
    float* __restrict__ zq, float* __restrict__ indOut)
{
    const int p = blockIdx.x * 256 + threadIdx.x;
    const unsigned long long pk = best[p];
    const int idx = (int)(~(unsigned)pk);

    const float4* e = reinterpret_cast<const float4*>(emb + (size_t)idx * Dc);
    const int b  = p >> 10;
    const int hw = p & (HWc - 1);
    float* o = zq + (size_t)b * Dc * HWc + hw;
#pragma unroll
    for (int q = 0; q < 8; ++q) {
        const float4 v = e[q];
        o[(size_t)(4*q+0) * HWc] = v.x;
        o[(size_t)(4*q+1) * HWc] = v.y;
        o[(size_t)(4*q+2) * HWc] = v.z;
        o[(size_t)(4*q+3) * HWc] = v.w;
    }
    indOut[p] = (float)idx;
}

extern "C" void kernel_launch(void* const* d_in, const int* in_sizes, int n_in,
                              void* d_out, int out_size, void* d_ws, size_t ws_size,
                              hipStream_t stream)
{
    const float* z   = (const float*)d_in[0];
    const float* emb = (const float*)d_in[1];

    float* out    = (float*)d_out;
    float* zq     = out;                          // 131072 floats
    float* indOut = out + (size_t)Bc * Dc * HWc;  // 4096 index values (as f32)

    unsigned long long* best = (unsigned long long*)d_ws;        // 32 KB
    _Float16* Es = (_Float16*)((char*)d_ws + (size_t)POS * 8);   // 4 MB
    const size_t needed = (size_t)POS * 8 + (size_t)NE * 64 * sizeof(_Float16);

    if (ws_size >= needed) {
        // eprep zeroes best[] -> no memset dispatch needed
        hipLaunchKernelGGL(vq_eprep, dim3(NE / 256), dim3(256), 0, stream,
                           emb, Es, best);
        hipLaunchKernelGGL(vq_mfma, dim3(2048), dim3(256), 0, stream,
                           z, Es, best);
    } else {
        hipMemsetAsync(best, 0, (size_t)POS * sizeof(unsigned long long), stream);
        hipLaunchKernelGGL(vq_scalar, dim3(2048), dim3(256), 0, stream,
                           z, emb, best);
    }
    hipLaunchKernelGGL(vq_finish_kernel, dim3(POS / 256), dim3(256), 0, stream,
                       best, emb, zq, indOut);
}

// Round 10
// 47.122 us; speedup vs baseline: 1.6796x; 1.6796x over previous
//
#include <hip/hip_runtime.h>
#include <math.h>

// Problem constants: z [4,32,32,32] f32, embedding [32768,32] f32.
constexpr int Bc   = 4;
constexpr int Dc   = 32;
constexpr int HWc  = 1024;
constexpr int NE   = 32768;
constexpr int POS  = Bc * HWc;        // 4096 positions

constexpr int CCODES = 256;           // codes per block chunk (32 KB in LDS)
constexpr int NCHUNK = NE / CCODES;   // 128
constexpr int NPBLK  = 16;            // pos-blocks of 256 positions

typedef _Float16 f16x8 __attribute__((ext_vector_type(8)));
typedef float    f32x4 __attribute__((ext_vector_type(4)));

// Monotonic float->uint encoding; pack with ~idx so that among equal values
// the SMALLER index wins under max (== jnp.argmax first-index rule).
__device__ inline unsigned long long packVI(float v, int idx) {
    unsigned u = __float_as_uint(v);
    u = (u & 0x80000000u) ? ~u : (u | 0x80000000u);
    return ((unsigned long long)u << 32) | (unsigned)(~idx);
}

// Prep: embedding fp32 [32768][32] -> Es fp16 [32768][64]: bytes 0..63 = hi
// (RNE fp16), bytes 64..127 = lo (fp16 of x-hi). hi+lo = x to ~2^-22.
// Also zeroes best[] (first 4096 threads) so no separate memset dispatch.
__global__ __launch_bounds__(256) void vq_eprep(
    const float* __restrict__ emb, _Float16* __restrict__ Es,
    unsigned long long* __restrict__ best)
{
    const int c = blockIdx.x * 256 + threadIdx.x;       // 0..32767
    if (c < POS) best[c] = 0ULL;   // encoded minimum: any real value wins

    const float4* src = reinterpret_cast<const float4*>(emb + (size_t)c * Dc);
    float x[Dc];
#pragma unroll
    for (int q = 0; q < 8; ++q) {
        const float4 v = src[q];
        x[4*q+0] = v.x; x[4*q+1] = v.y; x[4*q+2] = v.z; x[4*q+3] = v.w;
    }
    f16x8* dst = reinterpret_cast<f16x8*>(Es + (size_t)c * 64);
#pragma unroll
    for (int q = 0; q < 4; ++q) {
        f16x8 h, l;
#pragma unroll
        for (int r = 0; r < 8; ++r) {
            const float xv = x[8*q+r];
            const _Float16 hv = (_Float16)xv;
            h[r] = hv;
            l[r] = (_Float16)(xv - (float)hv);
        }
        dst[q]     = h;   // hi block
        dst[4 + q] = l;   // lo block
    }
}

// Main: split-fp16 MFMA (hi*hi + hi*lo + lo*hi, exact to ~2e-6; validated
// bit-exact rounds 8-9). Round-10 schedule: back to 4 pos-tiles/wave (round-8
// ILP: 12 MFMA per B-load-pair) but B now staged in LDS once per block --
// no vmcnt in the main loop, ds_read_b128 latency (~120cy) is pipelined by
// the compiler. LDS XOR-swizzle (col ^= row&7 on 16B columns, G4/T2): source
// pre-swizzled on the global address (global_load_lds writes linearly, m104),
// readers apply the same XOR. row&7 == m&7 is loop-invariant -> read address
// is a constant +2048B/iter; every consecutive-8-lane phase covers all 8
// col-groups -> conflict-free b128. XCD-pinned chunks: 16 x 32KB per XCD L2.
__global__ __launch_bounds__(256, 4) void vq_mfma(
    const float* __restrict__ z, const _Float16* __restrict__ Es,
    unsigned long long* __restrict__ best)
{
    __shared__ __align__(16) _Float16 elds[CCODES * 64];   // 32 KB

    const int lin  = blockIdx.x;               // 0..2047
    const int xcd  = lin & 7;                  // dispatch round-robins XCDs
    const int j    = lin >> 3;                 // 0..255
    const int chunk = xcd * (NCHUNK / 8) + (j & (NCHUNK / 8 - 1));
    const int pblk  = j >> 4;                  // 0..15
    const int tid  = threadIdx.x;
    const int wave = tid >> 6, lane = tid & 63;
    const int m = lane & 15, g = lane >> 4;

    // ---- stage chunk -> LDS via global_load_lds, source pre-swizzled ----
    {
        const char* src = (const char*)(Es + (size_t)chunk * CCODES * 64);
        char* dstbase = (char*)elds + wave * 1024;   // wave-uniform base
#pragma unroll
        for (int r = 0; r < 8; ++r) {
            const int o    = r * 256 + tid;          // 16B-chunk index
            const int row  = o >> 3;                 // code row 0..255
            const int ccol = o & 7;                  // 16B col 0..7
            const int soff = row * 128 + ((ccol ^ (row & 7)) << 4);
            __builtin_amdgcn_global_load_lds(
                (const __attribute__((address_space(1))) void*)(src + soff),
                (__attribute__((address_space(3))) void*)(dstbase + r * 4096),
                16, 0, 0);
        }
    }

    // ---- A fragments: 4 pos-tiles x (hi,lo); overlaps staging latency ----
    const int posBase = pblk * 256 + wave * 64;
    f16x8 Ahi[4], Alo[4];
#pragma unroll
    for (int t = 0; t < 4; ++t) {
        const int pos = posBase + t * 16 + m;
        const int b = pos >> 10, hw = pos & (HWc - 1);
        const float* zp = z + (size_t)b * Dc * HWc + hw;
#pragma unroll
        for (int q = 0; q < 8; ++q) {
            const float xv = zp[(size_t)(8 * g + q) * HWc];
            const _Float16 hv = (_Float16)xv;
            Ahi[t][q] = hv;
            Alo[t][q] = (_Float16)(xv - (float)hv);
        }
    }
#pragma unroll
    for (int t = 0; t < 4; ++t) asm volatile("" : "+v"(Ahi[t]), "+v"(Alo[t]));

    float bval[16];
    int   bidx[16];
#pragma unroll
    for (int i = 0; i < 16; ++i) { bval[i] = -INFINITY; bidx[i] = 0; }

    __syncthreads();   // staging complete (vmcnt(0) implied)

    // ---- scan 16 code-tiles from LDS ----
    const int cbase = chunk * CCODES;
    const char* lbase = (const char*)elds;
    // swizzled read offsets; row&7 == m&7 for every tile (ct*16 ≡ 0 mod 8)
    int bh_off = m * 128 + (( g      ^ (m & 7)) << 4);
    int bl_off = m * 128 + (((g + 4) ^ (m & 7)) << 4);
    int idxv = cbase + m;

#pragma unroll 2
    for (int ct = 0; ct < CCODES / 16; ++ct) {
        const f16x8 Bh = *reinterpret_cast<const f16x8*>(lbase + bh_off);
        const f16x8 Bl = *reinterpret_cast<const f16x8*>(lbase + bl_off);
        bh_off += 2048; bl_off += 2048;

#pragma unroll
        for (int t = 0; t < 4; ++t) {
            f32x4 acc = {0.f, 0.f, 0.f, 0.f};
            acc = __builtin_amdgcn_mfma_f32_16x16x32_f16(Ahi[t], Bh, acc, 0, 0, 0);
            acc = __builtin_amdgcn_mfma_f32_16x16x32_f16(Ahi[t], Bl, acc, 0, 0, 0);
            acc = __builtin_amdgcn_mfma_f32_16x16x32_f16(Alo[t], Bh, acc, 0, 0, 0);
#pragma unroll
            for (int r = 0; r < 4; ++r) {
                if (acc[r] > bval[t*4+r]) { bval[t*4+r] = acc[r]; bidx[t*4+r] = idxv; }
            }
        }
        idxv += 16;
    }

    // ---- pack (val,~idx), reduce across the 16 cols of each lane group ----
    unsigned long long pk[16];
#pragma unroll
    for (int i = 0; i < 16; ++i) pk[i] = packVI(bval[i], bidx[i]);
#pragma unroll
    for (int s = 1; s < 16; s <<= 1) {
#pragma unroll
        for (int i = 0; i < 16; ++i) {
            const unsigned long long o = __shfl_xor(pk[i], s, 64);
            if (o > pk[i]) pk[i] = o;
        }
    }
    // lane g*16+c commits pair (t=c>>2, r=c&3): row = base + t*16 + 4g + r.
    unsigned long long mine = pk[0];
#pragma unroll
    for (int i = 1; i < 16; ++i) if (m == i) mine = pk[i];   // static-index select
    const int row = posBase + (m >> 2) * 16 + 4 * g + (m & 3);
    atomicMax(best + row, mine);
}

// Fallback (ws too small for Es): scalar VALU scan, all 256 segments.
__global__ __launch_bounds__(256, 4) void vq_scalar(
    const float* __restrict__ z, const float* __restrict__ emb,
    unsigned long long* __restrict__ best)
{
    const int lin = blockIdx.x;           // 0..2047
    const int xcd = lin & 7, j = lin >> 3;
    const int seg    = xcd * 32 + (j & 31);   // 256 segments of 128 codes
    const int posgrp = j >> 5;                // 0..7

    const int t  = posgrp * 256 + threadIdx.x;
    const int p0 = t, p1 = t + POS / 2;
    const int b0 = p0 >> 10, hw0 = p0 & (HWc - 1);
    const int b1 = p1 >> 10, hw1 = p1 & (HWc - 1);
    const float* zp0 = z + (size_t)b0 * Dc * HWc + hw0;
    const float* zp1 = z + (size_t)b1 * Dc * HWc + hw1;

    float za[Dc], zb[Dc];
#pragma unroll
    for (int d = 0; d < Dc; ++d) {
        za[d] = zp0[(size_t)d * HWc];
        zb[d] = zp1[(size_t)d * HWc];
    }
#pragma unroll
    for (int d = 0; d < Dc; ++d) asm volatile("" : "+v"(za[d]), "+v"(zb[d]));

    const int c0 = seg * 128;
    const float4* e4 = reinterpret_cast<const float4*>(emb + (size_t)c0 * Dc);
    float v0 = -INFINITY, v1 = -INFINITY;
    int   i0 = c0, i1 = c0;
#pragma unroll 1
    for (int cc = 0; cc < 128; ++cc, e4 += 8) {
        float a0 = 0.f, a1 = 0.f;
#pragma unroll
        for (int q = 0; q < 8; ++q) {
            const float4 e = e4[q];
            a0 = fmaf(za[4*q+0], e.x, a0); a1 = fmaf(zb[4*q+0], e.x, a1);
            a0 = fmaf(za[4*q+1], e.y, a0); a1 = fmaf(zb[4*q+1], e.y, a1);
            a0 = fmaf(za[4*q+2], e.z, a0); a1 = fmaf(zb[4*q+2], e.z, a1);
            a0 = fmaf(za[4*q+3], e.w, a0); a1 = fmaf(zb[4*q+3], e.w, a1);
        }
        const int c = c0 + cc;
        if (a0 > v0) { v0 = a0; i0 = c; }
        if (a1 > v1) { v1 = a1; i1 = c; }
    }
    atomicMax(best + p0, packVI(v0, i0));
    atomicMax(best + p1, packVI(v1, i1));
}

// Finish: decode winner, gather embedding row (float4, exact fp32 values),
// write z_q [b,d,h,w] coalesced, index as float (<=32767 exact in fp32).
__global__ __launch_bounds__(256) void vq_finish_kernel(
    const unsigned long long* __restrict__ best, const float* __restrict__ emb,
    float* __restrict__ zq, float* __restrict__ indOut)
{
    const int p = blockIdx.x * 256 + threadIdx.x;
    const unsigned long long pk = best[p];
    const int idx = (int)(~(unsigned)pk);

    const float4* e = reinterpret_cast<const float4*>(emb + (size_t)idx * Dc);
    const int b  = p >> 10;
    const int hw = p & (HWc - 1);
    float* o = zq + (size_t)b * Dc * HWc + hw;
#pragma unroll
    for (int q = 0; q < 8; ++q) {
        const float4 v = e[q];
        o[(size_t)(4*q+0) * HWc] = v.x;
        o[(size_t)(4*q+1) * HWc] = v.y;
        o[(size_t)(4*q+2) * HWc] = v.z;
        o[(size_t)(4*q+3) * HWc] = v.w;
    }
    indOut[p] = (float)idx;
}

extern "C" void kernel_launch(void* const* d_in, const int* in_sizes, int n_in,
                              void* d_out, int out_size, void* d_ws, size_t ws_size,
                              hipStream_t stream)
{
    const float* z   = (const float*)d_in[0];
    const float* emb = (const float*)d_in[1];

    float* out    = (float*)d_out;
    float* zq     = out;                          // 131072 floats
    float* indOut = out + (size_t)Bc * Dc * HWc;  // 4096 index values (as f32)

    unsigned long long* best = (unsigned long long*)d_ws;        // 32 KB
    _Float16* Es = (_Float16*)((char*)d_ws + (size_t)POS * 8);   // 4 MB
    const size_t needed = (size_t)POS * 8 + (size_t)NE * 64 * sizeof(_Float16);

    if (ws_size >= needed) {
        // eprep zeroes best[] -> no memset dispatch needed
        hipLaunchKernelGGL(vq_eprep, dim3(NE / 256), dim3(256), 0, stream,
                           emb, Es, best);
        hipLaunchKernelGGL(vq_mfma, dim3(NCHUNK * NPBLK), dim3(256), 0, stream,
                           z, Es, best);
    } else {
        hipMemsetAsync(best, 0, (size_t)POS * sizeof(unsigned long long), stream);
        hipLaunchKernelGGL(vq_scalar, dim3(2048), dim3(256), 0, stream,
                           z, emb, best);
    }
    hipLaunchKernelGGL(vq_finish_kernel, dim3(POS / 256), dim3(256), 0, stream,
                       best, emb, zq, indOut);
}